// Round 6
// baseline (320.790 us; speedup 1.0000x reference)
//
#include <hip/hip_runtime.h>

// LearnableTensorSquare: out[z,k] = sum_ij (W@T)[k,i*128+j] * f[z,i] * f[z,j]
// f = [ones, features], Z=16384, N=128, K=128, DIM_TS=2080. All-f16 pipeline.
// k_wf : W -> frag-ready f16 layout (in ws, after K3).
// k_wt : v4: p-tile 32, 64-d steps, grid 1024 (4 blocks/CU, 16 waves/CU) ->
//        enough loads in flight to saturate HBM. LDS-transposed [p][d] tile.
// k_sum: sum the two d-chunk partials into ws.
// k_qf : v3: 512-thr blocks (8 waves, 64z x 32k per wave), half-phase 16 KB
//        B staging (dbuf 32 KB LDS -> 16 waves/CU), fi direct from features.

#define ZTOT 16384
#define NIN  127
#define KOUT 128
#define DTS  2080
#define PTOT 16384  // N*N

typedef _Float16 h8 __attribute__((ext_vector_type(8)));
typedef _Float16 h2 __attribute__((ext_vector_type(2)));
typedef float f32x4 __attribute__((ext_vector_type(4)));
typedef float f32x16 __attribute__((ext_vector_type(16)));

static __device__ __forceinline__ void gl16(const void* g, void* l) {
  __builtin_amdgcn_global_load_lds((const __attribute__((address_space(1))) unsigned int*)g,
                                   (__attribute__((address_space(3))) unsigned int*)l, 16, 0, 0);
}

static __device__ __forceinline__ unsigned int pk16(float a, float b) {
  return __builtin_bit_cast(unsigned int, __builtin_amdgcn_cvt_pkrtz(a, b));
}

// ---- k_wf: Wf[unit=s*8+kg][lane][e] = f16(W[kg*16+(lane&15)][s*32+(lane>>4)*8+e])
__global__ __launch_bounds__(256) void k_wf(const float* __restrict__ W,
                                            _Float16* __restrict__ Wf) {
  const int t = threadIdx.x, lane = t & 63;
  const int unit = blockIdx.x * 4 + (t >> 6);
  if (unit >= 520) return;
  const int s = unit >> 3, kg = unit & 7;
  const int krow = kg * 16 + (lane & 15);
  const int dbase = s * 32 + ((lane >> 4) << 3);
  h8 v;
#pragma unroll
  for (int e = 0; e < 8; ++e) v[e] = (_Float16)W[(size_t)krow * DTS + dbase + e];
  *(h8*)(Wf + ((size_t)unit * 64 + lane) * 8) = v;
}

// ---- k_wt v4: K3part[chunk][k][p] = sum_{d in chunk} W[k][d]*T[d][p], f16.
// grid 1024 = 512 p-tiles(32) x 2 chunks (chunk0: d 0..1023, chunk1: 1024..2079).
// Per 64-d step: contiguous float4 loads of T row-pairs -> pkrtz -> swizzled
// [32 p][64 d] f16 LDS tile -> b128 B-frags + Wf A-frags. 4 blocks/CU.
__global__ __launch_bounds__(256, 4) void k_wt(const float* __restrict__ T,
                                               const _Float16* __restrict__ Wf,
                                               _Float16* __restrict__ K3a,
                                               _Float16* __restrict__ K3b) {
  __shared__ __align__(16) _Float16 Tb0[32 * 64];  // 4 KB, [p][d] swizzled
  __shared__ __align__(16) _Float16 Tb1[32 * 64];
  const int t = threadIdx.x, lane = t & 63, w = t >> 6;
  const int ptile = (int)blockIdx.x >> 1, chunk = (int)blockIdx.x & 1;
  const int p0 = ptile * 32;
  const int dbase = chunk ? 1024 : 0;
  _Float16* K3c = chunk ? K3b : K3a;

  // staging map: g = t&127, h = t>>7; p4 = g&7, dp = 2*(g>>3); d_loc = h*32+dp
  const int g = t & 127, h = t >> 7;
  const int p4 = g & 7, dp = 2 * (g >> 3);
  const int dloc = h * 32 + dp;
  const int u0w = dloc >> 3, bin = 2 * (dp & 7);
  const int l15 = lane & 15;

  const float* gT = T + (size_t)(dbase + dloc) * PTOT + p0 + 4 * p4;

#define LOADW(Q0, Q1, S)                                  \
  {                                                       \
    const float* gp = gT + (size_t)(S) * (64 * PTOT);     \
    Q0 = *(const float4*)gp;                              \
    Q1 = *(const float4*)(gp + PTOT);                     \
  }
#define WRITEW(BUF, Q0, Q1)                                             \
  {                                                                     \
    char* wb = (char*)(BUF);                                            \
    const int pr0 = p4 * 4;                                             \
    *(unsigned int*)(wb + (pr0 + 0) * 128 + ((u0w ^ ((pr0 + 0) & 7)) << 4) + bin) = pk16(Q0.x, Q1.x); \
    *(unsigned int*)(wb + (pr0 + 1) * 128 + ((u0w ^ ((pr0 + 1) & 7)) << 4) + bin) = pk16(Q0.y, Q1.y); \
    *(unsigned int*)(wb + (pr0 + 2) * 128 + ((u0w ^ ((pr0 + 2) & 7)) << 4) + bin) = pk16(Q0.z, Q1.z); \
    *(unsigned int*)(wb + (pr0 + 3) * 128 + ((u0w ^ ((pr0 + 3) & 7)) << 4) + bin) = pk16(Q0.w, Q1.w); \
  }
  // compute: wave w -> k rows w*32..+31; per sub-group sg(32 d) x nf(16 p): 2 MFMA
#define COMPUTEW(BUF, SGBASE)                                                        \
  {                                                                                  \
    _Pragma("unroll") for (int sg = 0; sg < 2; ++sg) {                               \
      const _Float16* wfp = Wf + (size_t)((SGBASE) + sg) * 4096 + w * 1024 + (size_t)lane * 8; \
      const h8 a0 = *(const h8*)wfp;                                                 \
      const h8 a1 = *(const h8*)(wfp + 512);                                         \
      _Pragma("unroll") for (int nf = 0; nf < 2; ++nf) {                             \
        const int row = nf * 16 + l15;                                               \
        const int u = (sg * 4 + (lane >> 4)) ^ (l15 & 7);                            \
        const h8 b = *(const h8*)((const char*)(BUF) + row * 128 + (u << 4));        \
        acc0[nf] = __builtin_amdgcn_mfma_f32_16x16x32_f16(a0, b, acc0[nf], 0, 0, 0); \
        acc1[nf] = __builtin_amdgcn_mfma_f32_16x16x32_f16(a1, b, acc1[nf], 0, 0, 0); \
      }                                                                              \
    }                                                                                \
  }

  f32x4 acc0[2] = {}, acc1[2] = {};
  float4 A0, A1, B0r, B1r, T0r, T1r;
  const int sgb = dbase >> 5;
  LOADW(A0, A1, 0)
  LOADW(B0r, B1r, 1)
  WRITEW(Tb0, A0, A1)
  __syncthreads();
  for (int s = 0; s < 16; s += 2) {
    if (s + 2 < 16) LOADW(A0, A1, s + 2)
    if (s + 2 == 16 && chunk && t < 128) {  // prefetch 32-d tail (d 2048..2079)
      const float* gp = T + (size_t)(2048 + dp) * PTOT + p0 + 4 * p4;
      T0r = *(const float4*)gp;
      T1r = *(const float4*)(gp + PTOT);
    }
    WRITEW(Tb1, B0r, B1r)
    COMPUTEW(Tb0, sgb + s * 2)
    __syncthreads();
    if (s + 3 < 16) LOADW(B0r, B1r, s + 3)
    if (s + 2 < 16) WRITEW(Tb0, A0, A1)
    COMPUTEW(Tb1, sgb + s * 2 + 2)
    __syncthreads();
  }
  if (chunk) {  // tail: 32 d at SG=64
    if (t < 128) WRITEW(Tb0, T0r, T1r)
    __syncthreads();
    {
      const _Float16* wfp = Wf + (size_t)64 * 4096 + w * 1024 + (size_t)lane * 8;
      const h8 a0 = *(const h8*)wfp;
      const h8 a1 = *(const h8*)(wfp + 512);
#pragma unroll
      for (int nf = 0; nf < 2; ++nf) {
        const int row = nf * 16 + l15;
        const int u = (lane >> 4) ^ (l15 & 7);
        const h8 b = *(const h8*)((const char*)Tb0 + row * 128 + (u << 4));
        acc0[nf] = __builtin_amdgcn_mfma_f32_16x16x32_f16(a0, b, acc0[nf], 0, 0, 0);
        acc1[nf] = __builtin_amdgcn_mfma_f32_16x16x32_f16(a1, b, acc1[nf], 0, 0, 0);
      }
    }
  }
  const int rb = (lane >> 4) << 2;
#pragma unroll
  for (int nf = 0; nf < 2; ++nf)
#pragma unroll
    for (int r = 0; r < 4; ++r) {
      K3c[(size_t)(w * 32 + rb + r) * PTOT + p0 + nf * 16 + l15] = (_Float16)acc0[nf][r];
      K3c[(size_t)(w * 32 + 16 + rb + r) * PTOT + p0 + nf * 16 + l15] = (_Float16)acc1[nf][r];
    }
#undef LOADW
#undef WRITEW
#undef COMPUTEW
}

// ---- k_sum: K3h = K3a + K3b (f16, 2M elems)
__global__ __launch_bounds__(256) void k_sum(const _Float16* __restrict__ A,
                                             const _Float16* __restrict__ B,
                                             _Float16* __restrict__ O) {
  const size_t i = ((size_t)blockIdx.x * 256 + threadIdx.x) * 8;
  const h8 a = *(const h8*)(A + i);
  const h8 b = *(const h8*)(B + i);
  *(h8*)(O + i) = a + b;
}

// ---- k_qf v3: grid 512 = 128 z-tiles(128) x 4 i-chunks; block 512 = 8 waves
// (zg 2 x kg 4). Wave: 64z x 32k. Half-phase = (i, j-half): B slice [128k][64j]
// 16 KB, dbuf. fj in regs (64 VGPR), acc 32 VGPR -> 4 waves/SIMD.
__global__ __launch_bounds__(512, 4) void k_qf(const float* __restrict__ features,
                                               const _Float16* __restrict__ K3,
                                               float* __restrict__ out) {
  __shared__ __align__(16) _Float16 Bh0[8192];  // 16 KB
  __shared__ __align__(16) _Float16 Bh1[8192];  // 16 KB
  const int t = threadIdx.x, lane = t & 63, w = t >> 6;  // w 0..7
  const int zg = w >> 2, kg = w & 3, hg = lane >> 5, l31 = lane & 31;
  const int zb = (int)blockIdx.x >> 2, ic = (int)blockIdx.x & 2 ? ((int)blockIdx.x & 3) : ((int)blockIdx.x & 3);
  const int ic4 = (int)blockIdx.x & 3;
  const int z0 = zb * 128, i0 = ic4 * 32;
  (void)ic;

  // ---- f-tile halves (swizzled, reg-staged) + fj register preload
  {
    const int row = t >> 2, sub = t & 3, rs = row & 7;
    const float* fr = features + (size_t)(z0 + row) * NIN;
#pragma unroll
    for (int q = 0; q < 2; ++q) {
      h8 v;
#pragma unroll
      for (int e = 0; e < 8; ++e) {
        const int j = sub * 16 + q * 8 + e;
        v[e] = (j == 0) ? (_Float16)1.0f : (_Float16)fr[j - 1];
      }
      *(h8*)((char*)Bh0 + row * 128 + (((sub * 2 + q) ^ rs) << 4)) = v;
    }
  }
  __syncthreads();
  // stage half 1 (j 64..127) into Bh1 (concurrent with Bh0 reads)
  {
    const int row = t >> 2, sub = t & 3, rs = row & 7;
    const float* fr = features + (size_t)(z0 + row) * NIN;
#pragma unroll
    for (int q = 0; q < 2; ++q) {
      h8 v;
#pragma unroll
      for (int e = 0; e < 8; ++e) v[e] = (_Float16)fr[63 + sub * 16 + q * 8 + e];
      *(h8*)((char*)Bh1 + row * 128 + (((sub * 2 + q) ^ rs) << 4)) = v;
    }
  }
  h8 fj[2][8];
#pragma unroll
  for (int m = 0; m < 2; ++m) {
    const int rowm = zg * 64 + m * 32 + l31, rs = rowm & 7;
#pragma unroll
    for (int c = 0; c < 4; ++c)
      fj[m][c] = *(const h8*)((const char*)Bh0 + rowm * 128 + ((((c * 2 + hg)) ^ rs) << 4));
  }
  __syncthreads();
#pragma unroll
  for (int m = 0; m < 2; ++m) {
    const int rowm = zg * 64 + m * 32 + l31, rs = rowm & 7;
#pragma unroll
    for (int c = 0; c < 4; ++c)
      fj[m][4 + c] = *(const h8*)((const char*)Bh1 + rowm * 128 + ((((c * 2 + hg)) ^ rs) << 4));
  }

  // B staging: linear LDS dest, inverse-swizzled global source (rule #21)
#define STAGE(BUF, HP)                                                        \
  {                                                                           \
    const int i_ = (HP) >> 1, jh_ = (HP) & 1;                                 \
    const _Float16* src = K3 + (size_t)(i0 + i_) * 128 + jh_ * 64;            \
    _Pragma("unroll") for (int r = 0; r < 2; ++r) {                           \
      const int rowb = (w * 2 + r) * 8 + (lane >> 3);                         \
      gl16(src + (size_t)rowb * PTOT + (((lane & 7) ^ (lane >> 3)) << 3),     \
           (char*)(BUF) + (w * 2 + r) * 1024);                                \
    }                                                                         \
  }
#define COMPUTE(BUF, CBASE)                                                   \
  {                                                                           \
    _Pragma("unroll") for (int kc = 0; kc < 4; ++kc) {                        \
      const int c = (CBASE) + kc;                                             \
      const h8 fjA = fj[0][c], fjB = fj[1][c];                                \
      h8 a0, a1;                                                              \
      _Pragma("unroll") for (int r = 0; r < 4; ++r) {                         \
        const h2 j0 = {fjA[2 * r], fjA[2 * r + 1]};                           \
        const h2 j1 = {fjB[2 * r], fjB[2 * r + 1]};                           \
        const h2 p0 = fi0 * j0;                                               \
        const h2 p1 = fi1 * j1;                                               \
        a0[2 * r] = p0[0]; a0[2 * r + 1] = p0[1];                             \
        a1[2 * r] = p1[0]; a1[2 * r + 1] = p1[1];                             \
      }                                                                       \
      const h8 b = *(const h8*)((const char*)(BUF) + brow +                   \
                                (((kc * 2 + hg) ^ sl7) << 4));                \
      acc0 = __builtin_amdgcn_mfma_f32_32x32x16_f16(a0, b, acc0, 0, 0, 0);    \
      acc1 = __builtin_amdgcn_mfma_f32_32x32x16_f16(a1, b, acc1, 0, 0, 0);    \
    }                                                                         \
  }

  const int brow = (kg * 32 + l31) * 128;
  const int sl7 = l31 & 7;
  const size_t zrow0 = (size_t)(z0 + zg * 64 + l31) * NIN;
  const size_t zrow1 = (size_t)(z0 + zg * 64 + 32 + l31) * NIN;

  f32x16 acc0 = {}, acc1 = {};
  float fn0 = (i0 == 0) ? 1.0f : features[zrow0 + i0 - 1];
  float fn1 = (i0 == 0) ? 1.0f : features[zrow1 + i0 - 1];
  STAGE(Bh0, 0)
  __syncthreads();

  h2 fi0, fi1;
  for (int pb = 0; pb < 32; ++pb) {
    {
      const _Float16 c0 = (_Float16)fn0, c1 = (_Float16)fn1;
      fi0 = (h2){c0, c0};
      fi1 = (h2){c1, c1};
    }
    if (pb < 31) {  // prefetch next fi (index i0+pb+1, never the ones channel)
      fn0 = features[zrow0 + i0 + pb];
      fn1 = features[zrow1 + i0 + pb];
    }
    STAGE(Bh1, 2 * pb + 1)
    COMPUTE(Bh0, 0)
    __syncthreads();
    if (pb < 31) STAGE(Bh0, 2 * pb + 2)
    COMPUTE(Bh1, 4)
    __syncthreads();
  }

  // C/D 32x32: col = l31 (k), row = (r&3) + 8*(r>>2) + 4*hg (z)
  const int kq = kg * 32 + l31;
#pragma unroll
  for (int r = 0; r < 16; ++r) {
    const int zr = (r & 3) + ((r >> 2) << 3) + (hg << 2);
    atomicAdd(out + (size_t)(z0 + zg * 64 + zr) * KOUT + kq, acc0[r]);
    atomicAdd(out + (size_t)(z0 + zg * 64 + 32 + zr) * KOUT + kq, acc1[r]);
  }
#undef STAGE
#undef COMPUTE
}

extern "C" void kernel_launch(void* const* d_in, const int* in_sizes, int n_in,
                              void* d_out, int out_size, void* d_ws, size_t ws_size,
                              hipStream_t stream) {
  const float* features = (const float*)d_in[0];  // [16384, 127]
  const float* W        = (const float*)d_in[1];  // [128, 2080]
  const float* T        = (const float*)d_in[2];  // [2080, 16384]
  float* out = (float*)d_out;                     // [16384, 128] f32

  _Float16* K3h = (_Float16*)d_ws;                // [128, 16384] f16 (4 MB)
  _Float16* Wf  = K3h + (size_t)2 * 1024 * 1024;  // 532 KB, ws total ~4.6 MB
  _Float16* K3a = (_Float16*)d_out;               // partials in d_out scratch (8 MB)
  _Float16* K3b = K3a + (size_t)2 * 1024 * 1024;

  k_wf<<<dim3(130), dim3(256), 0, stream>>>(W, Wf);
  k_wt<<<dim3(1024), dim3(256), 0, stream>>>(T, Wf, K3a, K3b);
  k_sum<<<dim3(1024), dim3(256), 0, stream>>>(K3a, K3b, K3h);
  (void)hipMemsetAsync(d_out, 0, (size_t)ZTOT * KOUT * sizeof(float), stream);
  k_qf<<<dim3(512), dim3(512), 0, stream>>>(features, K3h, out);
}

// Round 7
// 299.144 us; speedup vs baseline: 1.0724x; 1.0724x over previous
//
#include <hip/hip_runtime.h>

// LearnableTensorSquare: out[z,k] = sum_ij (W@T)[k,i*128+j] * f[z,i] * f[z,j]
// f = [ones, features], Z=16384, N=128, K=128, DIM_TS=2080. All-f16 pipeline.
// k_wf : W -> frag-ready f16 layout (in ws, after K3).
// k_wt : v3 geometry (64-p tiles, LDS-transposed [p][d]) + RAW barriers
//        (lgkmcnt(0)+s_barrier, no vmcnt drain) so reg prefetch spans barriers.
// k_sum: sum the two d-chunk partials into ws.
// k_qf : R5 geometry (4 waves, 64z x 64k, A in regs) + counted-vmcnt pipeline:
//        4 x 16KB (i, j-half) buffers, stage 3 ahead, vmcnt(12), raw barriers,
//        setprio around MFMA cluster, sched_barrier(0) fences.

#define ZTOT 16384
#define NIN  127
#define KOUT 128
#define DTS  2080
#define PTOT 16384  // N*N

typedef _Float16 h8 __attribute__((ext_vector_type(8)));
typedef _Float16 h2 __attribute__((ext_vector_type(2)));
typedef float f32x4 __attribute__((ext_vector_type(4)));
typedef float f32x16 __attribute__((ext_vector_type(16)));

static __device__ __forceinline__ void gl16(const void* g, void* l) {
  __builtin_amdgcn_global_load_lds((const __attribute__((address_space(1))) unsigned int*)g,
                                   (__attribute__((address_space(3))) unsigned int*)l, 16, 0, 0);
}

static __device__ __forceinline__ unsigned int pk16(float a, float b) {
  return __builtin_bit_cast(unsigned int, __builtin_amdgcn_cvt_pkrtz(a, b));
}

// raw barrier: drain LDS ops only (NOT vmcnt) so global prefetch stays in flight
#define BARW                                                \
  {                                                         \
    asm volatile("s_waitcnt lgkmcnt(0)" ::: "memory");      \
    __builtin_amdgcn_s_barrier();                           \
    __builtin_amdgcn_sched_barrier(0);                      \
  }

// ---- k_wf: Wf[unit=s*8+kg][lane][e] = f16(W[kg*16+(lane&15)][s*32+(lane>>4)*8+e])
__global__ __launch_bounds__(256) void k_wf(const float* __restrict__ W,
                                            _Float16* __restrict__ Wf) {
  const int t = threadIdx.x, lane = t & 63;
  const int unit = blockIdx.x * 4 + (t >> 6);
  if (unit >= 520) return;
  const int s = unit >> 3, kg = unit & 7;
  const int krow = kg * 16 + (lane & 15);
  const int dbase = s * 32 + ((lane >> 4) << 3);
  h8 v;
#pragma unroll
  for (int e = 0; e < 8; ++e) v[e] = (_Float16)W[(size_t)krow * DTS + dbase + e];
  *(h8*)(Wf + ((size_t)unit * 64 + lane) * 8) = v;
}

// ---- k_wt v3 + raw barriers: K3part[chunk][k][p] = sum_{d in chunk} W[k][d]*T[d][p].
// grid 512 = 256 p-tiles(64) x 2 d-chunks (33/32 steps of 32 d). Block 256 = 4 waves.
__global__ __launch_bounds__(256, 2) void k_wt(const float* __restrict__ T,
                                               const _Float16* __restrict__ Wf,
                                               _Float16* __restrict__ K3a,
                                               _Float16* __restrict__ K3b) {
  __shared__ __align__(16) _Float16 Tb0[64 * 32];
  __shared__ __align__(16) _Float16 Tb1[64 * 32];
  const int t = threadIdx.x, lane = t & 63, w = t >> 6;
  const int ptile = (int)blockIdx.x >> 1, chunk = (int)blockIdx.x & 1;
  const int p0 = ptile * 64;
  const int sb = chunk ? 33 : 0, ns = chunk ? 32 : 33;
  _Float16* K3c = chunk ? K3b : K3a;

  const int p4 = t & 15, dp = 2 * (t >> 4);  // thread stages rows (dp, dp+1), p = 4*p4..
  const int wbase = 256 * p4 + 16 * ((dp >> 3) ^ (p4 & 3)) + 2 * (dp & 7);
  const int l15 = lane & 15;
  const int su = 16 * ((lane >> 4) ^ (l15 >> 2));  // read swizzle (nf-independent)

  const float* gT = T + (size_t)(sb * 32 + dp) * PTOT + p0 + 4 * p4;

#define LOADW(Q0, Q1, S)                                      \
  {                                                           \
    const float* gp = gT + (size_t)(S) * (32 * PTOT);         \
    Q0 = *(const float4*)gp;                                  \
    Q1 = *(const float4*)(gp + PTOT);                         \
  }
#define WRITEW(BUF, Q0, Q1)                                   \
  {                                                           \
    char* wb = (char*)(BUF) + wbase;                          \
    *(unsigned int*)(wb + 0)   = pk16(Q0.x, Q1.x);            \
    *(unsigned int*)(wb + 64)  = pk16(Q0.y, Q1.y);            \
    *(unsigned int*)(wb + 128) = pk16(Q0.z, Q1.z);            \
    *(unsigned int*)(wb + 192) = pk16(Q0.w, Q1.w);            \
  }
#define COMPUTEW(BUF, SG)                                                         \
  {                                                                               \
    const _Float16* wfp = Wf + (size_t)(SG) * 4096 + w * 1024 + (size_t)lane * 8; \
    const h8 a0 = *(const h8*)wfp;                                                \
    const h8 a1 = *(const h8*)(wfp + 512);                                        \
    _Pragma("unroll") for (int nf = 0; nf < 4; ++nf) {                            \
      const h8 b = *(const h8*)((const char*)(BUF) + 64 * (nf * 16 + l15) + su);  \
      acc0[nf] = __builtin_amdgcn_mfma_f32_16x16x32_f16(a0, b, acc0[nf], 0, 0, 0); \
      acc1[nf] = __builtin_amdgcn_mfma_f32_16x16x32_f16(a1, b, acc1[nf], 0, 0, 0); \
    }                                                                             \
  }

  f32x4 acc0[4] = {}, acc1[4] = {};
  float4 A0, A1, Br0, Br1;
  LOADW(A0, A1, 0)
  LOADW(Br0, Br1, 1)
  WRITEW(Tb0, A0, A1)
  BARW
  for (int s = 0; s < ns; s += 2) {
    if (s + 2 < ns) LOADW(A0, A1, s + 2)
    if (s + 1 < ns) WRITEW(Tb1, Br0, Br1)
    COMPUTEW(Tb0, sb + s)
    BARW
    if (s + 1 < ns) {
      if (s + 3 < ns) LOADW(Br0, Br1, s + 3)
      if (s + 2 < ns) WRITEW(Tb0, A0, A1)
      COMPUTEW(Tb1, sb + s + 1)
      BARW
    }
  }
  const int rb = (lane >> 4) << 2;
#pragma unroll
  for (int nf = 0; nf < 4; ++nf)
#pragma unroll
    for (int r = 0; r < 4; ++r) {
      K3c[(size_t)(w * 32 + rb + r) * PTOT + p0 + nf * 16 + l15] = (_Float16)acc0[nf][r];
      K3c[(size_t)(w * 32 + 16 + rb + r) * PTOT + p0 + nf * 16 + l15] = (_Float16)acc1[nf][r];
    }
#undef LOADW
#undef WRITEW
#undef COMPUTEW
}

// ---- k_sum: K3h = K3a + K3b (f16, 2M elems)
__global__ __launch_bounds__(256) void k_sum(const _Float16* __restrict__ A,
                                             const _Float16* __restrict__ B,
                                             _Float16* __restrict__ O) {
  const size_t i = ((size_t)blockIdx.x * 256 + threadIdx.x) * 8;
  const h8 a = *(const h8*)(A + i);
  const h8 b = *(const h8*)(B + i);
  *(h8*)(O + i) = a + b;
}

// ---- k_qf v4: grid 512 = 128 z-tiles x 4 i-chunks; block 256 = 4 waves (2zg x 2kg).
// Wave 64z x 64k. Phases = (i, j-half): B slice [128k][64j] = 16 KB; 4 buffers,
// stage 3 ahead (4 gl16/wave each), s_waitcnt vmcnt(12), raw barriers, setprio.
__global__ __launch_bounds__(256, 2) void k_qf(const float* __restrict__ features,
                                               const _Float16* __restrict__ K3,
                                               float* __restrict__ out) {
  __shared__ __align__(16) _Float16 Bq[32768];  // 64 KB = 4 x 16 KB buffers
  __shared__ _Float16 fT[32 * 136];
  const int t = threadIdx.x, lane = t & 63, w = t >> 6;
  const int zg = w >> 1, kg = w & 1, hg = lane >> 5, l31 = lane & 31;
  const int zb = (int)blockIdx.x >> 2, ic = (int)blockIdx.x & 3;
  const int z0 = zb * 128, i0 = ic * 32;

  // f-tile [z 0..127][j 0..127] f16, XOR-swizzled, into Bq[0..31KB] (transient)
  {
    const int row = t >> 1, hf = t & 1;
    const float* fr = features + (size_t)(z0 + row) * NIN;
    const int rs = (row & 7) << 4;
#pragma unroll
    for (int qb = 0; qb < 8; ++qb) {
      h8 v;
#pragma unroll
      for (int e = 0; e < 8; ++e) {
        const int j = hf * 64 + qb * 8 + e;
        v[e] = (j == 0) ? (_Float16)1.0f : (_Float16)fr[j - 1];
      }
      *(h8*)((char*)Bq + row * 256 + (((hf * 8 + qb) * 16) ^ rs)) = v;
    }
  }
  // fT[i 0..31][z 0..127] (fi lookup, transposed; ds-resident so vmcnt stays clean)
  {
    const int z = t >> 1, ih = t & 1;
#pragma unroll
    for (int q = 0; q < 16; ++q) {
      const int il = ih * 16 + q, gi = i0 + il;
      const float fv = (gi == 0) ? 1.0f : features[(size_t)(z0 + z) * NIN + gi - 1];
      fT[il * 136 + z] = (_Float16)fv;
    }
  }
  __syncthreads();

  // fj regs: rows (zg*64 + m*32 + l31), j = c*16 + hg*8 + e, c 0..7
  h8 fj8[2][8];
#pragma unroll
  for (int m = 0; m < 2; ++m) {
    const int rowm = zg * 64 + m * 32 + l31;
    const int rs = (rowm & 7) << 4;
#pragma unroll
    for (int c = 0; c < 8; ++c)
      fj8[m][c] = *(const h8*)((const char*)Bq + rowm * 256 + (((c * 2 + hg) * 16) ^ rs));
  }
  __syncthreads();  // fj reads done before staging overwrites Bq

  const int sl7 = l31 & 7;
  const int brow0 = (kg * 64 + l31) * 128;        // 128 B rows in half-tiles
  const int brow1 = (kg * 64 + 32 + l31) * 128;
  f32x16 acc[2][2] = {};

  // stage phase P = (i_local, j_half) into buffer BI: linear LDS dest,
  // inverse-swizzled global source (rule #21). 4 gl16 per wave.
#define STAGEQ(BI, P)                                                            \
  {                                                                              \
    const _Float16* src = K3 + (size_t)(i0 + ((P) >> 1)) * 128 + ((P) & 1) * 64; \
    _Pragma("unroll") for (int r = 0; r < 4; ++r) {                              \
      const int rowb = w * 32 + r * 8 + (lane >> 3);                             \
      gl16(src + (size_t)rowb * PTOT + (((lane & 7) ^ (lane >> 3)) << 3),        \
           (char*)Bq + (BI) * 16384 + w * 4096 + r * 1024);                      \
    }                                                                            \
  }

#define PHASEQ(BI, CB, IPH, DOST, SP, VM)                                        \
  {                                                                              \
    if (DOST) STAGEQ((SP) & 3, SP)                                               \
    const _Float16 f0s = fT[(IPH) * 136 + zg * 64 + l31];                        \
    const _Float16 f1s = fT[(IPH) * 136 + zg * 64 + 32 + l31];                   \
    const h2 fi0 = {f0s, f0s};                                                   \
    const h2 fi1 = {f1s, f1s};                                                   \
    h8 a0[4], a1[4];                                                             \
    _Pragma("unroll") for (int kl = 0; kl < 4; ++kl) {                           \
      const h8 fjA = fj8[0][(CB) + kl], fjB = fj8[1][(CB) + kl];                 \
      _Pragma("unroll") for (int r = 0; r < 4; ++r) {                            \
        const h2 j0 = {fjA[2 * r], fjA[2 * r + 1]};                              \
        const h2 j1 = {fjB[2 * r], fjB[2 * r + 1]};                              \
        const h2 q0 = fi0 * j0;                                                  \
        const h2 q1 = fi1 * j1;                                                  \
        a0[kl][2 * r] = q0[0]; a0[kl][2 * r + 1] = q0[1];                        \
        a1[kl][2 * r] = q1[0]; a1[kl][2 * r + 1] = q1[1];                        \
      }                                                                          \
    }                                                                            \
    asm volatile("s_waitcnt vmcnt(" #VM ")" ::: "memory");                       \
    __builtin_amdgcn_s_barrier();                                                \
    __builtin_amdgcn_sched_barrier(0);                                           \
    __builtin_amdgcn_s_setprio(1);                                               \
    const char* bp = (const char*)Bq + (BI) * 16384;                             \
    _Pragma("unroll") for (int kl = 0; kl < 4; ++kl) {                           \
      const int ur = ((kl * 2 + hg) ^ sl7) << 4;                                 \
      const h8 b0 = *(const h8*)(bp + brow0 + ur);                               \
      const h8 b1 = *(const h8*)(bp + brow1 + ur);                               \
      acc[0][0] = __builtin_amdgcn_mfma_f32_32x32x16_f16(a0[kl], b0, acc[0][0], 0, 0, 0); \
      acc[0][1] = __builtin_amdgcn_mfma_f32_32x32x16_f16(a0[kl], b1, acc[0][1], 0, 0, 0); \
      acc[1][0] = __builtin_amdgcn_mfma_f32_32x32x16_f16(a1[kl], b0, acc[1][0], 0, 0, 0); \
      acc[1][1] = __builtin_amdgcn_mfma_f32_32x32x16_f16(a1[kl], b1, acc[1][1], 0, 0, 0); \
    }                                                                            \
    __builtin_amdgcn_s_setprio(0);                                               \
    __builtin_amdgcn_sched_barrier(0);                                           \
    __builtin_amdgcn_s_barrier();                                                \
  }

  // prologue: 3 stages in flight (12 loads)
  STAGEQ(0, 0)
  STAGEQ(1, 1)
  STAGEQ(2, 2)
  for (int pb = 0; pb < 30; ++pb) {
    PHASEQ((2 * pb) & 3, 0, pb, 1, 2 * pb + 3, 12)
    PHASEQ((2 * pb + 1) & 3, 4, pb, 1, 2 * pb + 4, 12)
  }
  PHASEQ(0, 0, 30, 1, 63, 12)  // phase 60, stages phase 63
  PHASEQ(1, 4, 30, 0, 0, 8)    // phase 61
  PHASEQ(2, 0, 31, 0, 0, 4)    // phase 62
  PHASEQ(3, 4, 31, 0, 0, 0)    // phase 63
#undef STAGEQ
#undef PHASEQ

  // C/D 32x32: col = l31 (k), row = (r&3) + 8*(r>>2) + 4*hg (z)
  const int kq = kg * 64 + l31;
#pragma unroll
  for (int m = 0; m < 2; ++m)
#pragma unroll
    for (int n = 0; n < 2; ++n)
#pragma unroll
      for (int r = 0; r < 16; ++r) {
        const int zr = (r & 3) + ((r >> 2) << 3) + (hg << 2);
        const int z = z0 + zg * 64 + m * 32 + zr;
        atomicAdd(out + (size_t)z * KOUT + kq + n * 32, acc[m][n][r]);
      }
}

extern "C" void kernel_launch(void* const* d_in, const int* in_sizes, int n_in,
                              void* d_out, int out_size, void* d_ws, size_t ws_size,
                              hipStream_t stream) {
  const float* features = (const float*)d_in[0];  // [16384, 127]
  const float* W        = (const float*)d_in[1];  // [128, 2080]
  const float* T        = (const float*)d_in[2];  // [2080, 16384]
  float* out = (float*)d_out;                     // [16384, 128] f32

  _Float16* K3h = (_Float16*)d_ws;                // [128, 16384] f16 (4 MB)
  _Float16* Wf  = K3h + (size_t)2 * 1024 * 1024;  // 532 KB, ws total ~4.6 MB
  _Float16* K3a = (_Float16*)d_out;               // partials in d_out scratch (8 MB)
  _Float16* K3b = K3a + (size_t)2 * 1024 * 1024;

  k_wf<<<dim3(130), dim3(256), 0, stream>>>(W, Wf);
  k_wt<<<dim3(512), dim3(256), 0, stream>>>(T, Wf, K3a, K3b);
  k_sum<<<dim3(1024), dim3(256), 0, stream>>>(K3a, K3b, K3h);
  (void)hipMemsetAsync(d_out, 0, (size_t)ZTOT * KOUT * sizeof(float), stream);
  k_qf<<<dim3(512), dim3(256), 0, stream>>>(features, K3h, out);
}

// Round 8
// 296.785 us; speedup vs baseline: 1.0809x; 1.0080x over previous
//
#include <hip/hip_runtime.h>

// LearnableTensorSquare: out[z,k] = sum_ij (W@T)[k,i*128+j] * f[z,i] * f[z,j]
// f = [ones, features], Z=16384, N=128, K=128, DIM_TS=2080. All-f16 pipeline.
// k_wf : W -> frag-ready f16 layout, K-permuted (pi) to match k_wt's LDS slots.
// k_wt : v5 page-friendly: p-tile 128 (512B row reads), grid 256 (1 blk/CU),
//        depth-2 reg ring, LDS dbuf with pi-permuted [p][d] slots (b64 writes,
//        conflict-free b128 reads). Partials -> d_out scratch.
// k_sum: sum the two d-chunk partials into ws.
// k_qf : v5: 4-buf counted-vmcnt pipeline, ONE barrier/phase (stage after
//        barrier), vmcnt(8); fT stride 140 + packed writes.

#define ZTOT 16384
#define NIN  127
#define KOUT 128
#define DTS  2080
#define PTOT 16384  // N*N

typedef _Float16 h8 __attribute__((ext_vector_type(8)));
typedef _Float16 h2 __attribute__((ext_vector_type(2)));
typedef float f32x4 __attribute__((ext_vector_type(4)));
typedef float f32x16 __attribute__((ext_vector_type(16)));

static __device__ __forceinline__ void gl16(const void* g, void* l) {
  __builtin_amdgcn_global_load_lds((const __attribute__((address_space(1))) unsigned int*)g,
                                   (__attribute__((address_space(3))) unsigned int*)l, 16, 0, 0);
}

static __device__ __forceinline__ unsigned int pk16(float a, float b) {
  return __builtin_bit_cast(unsigned int, __builtin_amdgcn_cvt_pkrtz(a, b));
}

// raw barrier: drain LDS ops only (NOT vmcnt)
#define BARW                                                \
  {                                                         \
    asm volatile("s_waitcnt lgkmcnt(0)" ::: "memory");      \
    __builtin_amdgcn_s_barrier();                           \
    __builtin_amdgcn_sched_barrier(0);                      \
  }

// ---- k_wf: Wf[unit=s*8+kg][lane][e] = f16(W[kg*16+(lane&15)][s*32 + pi_q(e)])
// pi_q(e) = e<4 ? 2q+8e : 2q+1+8(e-4), q = lane>>4. (K-permutation shared with k_wt.)
__global__ __launch_bounds__(256) void k_wf(const float* __restrict__ W,
                                            _Float16* __restrict__ Wf) {
  const int t = threadIdx.x, lane = t & 63;
  const int unit = blockIdx.x * 4 + (t >> 6);
  if (unit >= 520) return;
  const int s = unit >> 3, kg = unit & 7;
  const int krow = kg * 16 + (lane & 15);
  const int q = (lane >> 4) & 3;
  h8 v;
#pragma unroll
  for (int e = 0; e < 8; ++e) {
    const int doff = (e < 4) ? (2 * q + 8 * e) : (2 * q + 1 + 8 * (e - 4));
    v[e] = (_Float16)W[(size_t)krow * DTS + s * 32 + doff];
  }
  *(h8*)(Wf + ((size_t)unit * 64 + lane) * 8) = v;
}

// ---- k_wt v5: K3part[chunk][k][p] = sum_{d in chunk} W[k][d]*T[d][p], f16.
// grid 256 = 128 p-tiles(128) x 2 chunks (32/33 steps of 32 d). Block 256 = 4 waves.
// Wave w: k-rows w*32..+31 (all waves read full [128p][32d] tile).
__global__ __launch_bounds__(256) void k_wt(const float* __restrict__ T,
                                            const _Float16* __restrict__ Wf,
                                            _Float16* __restrict__ K3a,
                                            _Float16* __restrict__ K3b) {
  __shared__ __align__(16) _Float16 Tb0[128 * 32];  // 8 KB, pi-permuted slots
  __shared__ __align__(16) _Float16 Tb1[128 * 32];
  const int t = threadIdx.x, lane = t & 63, w = t >> 6;
  const int pt = (int)blockIdx.x >> 1, chunk = (int)blockIdx.x & 1;
  const int p0 = pt * 128;
  const int sgb = chunk ? 32 : 0, ns = chunk ? 33 : 32;
  _Float16* K3c = chunk ? K3b : K3a;
  const int hb = lane >> 5, l31 = lane & 31, l15 = lane & 15, q = (lane >> 4) & 3;
  const int c = 2 * w + hb;  // d-slot index 0..7

  const float* gT = T + (size_t)(sgb * 32 + c) * PTOT + p0 + l31 * 4;

#define LOADQ(Q, S)                                                    \
  {                                                                    \
    const float* gp = gT + (size_t)(S) * (32 * PTOT);                  \
    _Pragma("unroll") for (int li = 0; li < 4; ++li)                   \
        Q[li] = *(const f32x4*)(gp + (size_t)li * 8 * PTOT);           \
  }
  // b64 at [p][unit (w^g)], half hb: holds d-quad {c, c+8, c+16, c+24}
#define WRITEQ(BUF, Q)                                                            \
  {                                                                               \
    _Pragma("unroll") for (int po = 0; po < 4; ++po) {                            \
      const int p_ = l31 * 4 + po;                                                \
      const int g_ = ((p_ >> 1) ^ (p_ >> 4)) & 3;                                 \
      unsigned long long v_ = (unsigned long long)pk16(Q[0][po], Q[1][po]) |      \
                              ((unsigned long long)pk16(Q[2][po], Q[3][po]) << 32); \
      *(unsigned long long*)((char*)(BUF) + p_ * 64 + (((w ^ g_) & 3) << 4) +     \
                             hb * 8) = v_;                                        \
    }                                                                             \
  }
#define COMPUTEQ(BUF, SG)                                                          \
  {                                                                                \
    const _Float16* wfp = Wf + (size_t)(SG) * 4096 + w * 1024 + (size_t)lane * 8;  \
    const h8 a0 = *(const h8*)wfp;                                                 \
    const h8 a1 = *(const h8*)(wfp + 512);                                         \
    _Pragma("unroll") for (int nf = 0; nf < 8; ++nf) {                             \
      const int row = nf * 16 + l15;                                               \
      const int g_ = ((row >> 1) ^ (row >> 4)) & 3;                                \
      const h8 b = *(const h8*)((const char*)(BUF) + row * 64 + (((q ^ g_) & 3) << 4)); \
      acc0[nf] = __builtin_amdgcn_mfma_f32_16x16x32_f16(a0, b, acc0[nf], 0, 0, 0); \
      acc1[nf] = __builtin_amdgcn_mfma_f32_16x16x32_f16(a1, b, acc1[nf], 0, 0, 0); \
    }                                                                              \
  }

  f32x4 acc0[8] = {}, acc1[8] = {};
  f32x4 QA[4], QB[4];
  LOADQ(QA, 0)
  if (ns > 1) LOADQ(QB, 1)
  for (int s = 0; s < ns; s += 2) {
    WRITEQ(Tb0, QA)
    if (s + 2 < ns) LOADQ(QA, s + 2)
    BARW
    COMPUTEQ(Tb0, sgb + s)
    if (s + 1 < ns) {
      WRITEQ(Tb1, QB)
      if (s + 3 < ns) LOADQ(QB, s + 3)
      BARW
      COMPUTEQ(Tb1, sgb + s + 1)
    }
  }
  // C 16x16: col = l15 (p), row = q*4 + r (k within 16)
#pragma unroll
  for (int nf = 0; nf < 8; ++nf)
#pragma unroll
    for (int r = 0; r < 4; ++r) {
      K3c[(size_t)(w * 32 + q * 4 + r) * PTOT + p0 + nf * 16 + l15] = (_Float16)acc0[nf][r];
      K3c[(size_t)(w * 32 + 16 + q * 4 + r) * PTOT + p0 + nf * 16 + l15] = (_Float16)acc1[nf][r];
    }
#undef LOADQ
#undef WRITEQ
#undef COMPUTEQ
}

// ---- k_sum: K3h = K3a + K3b (f16, 2M elems)
__global__ __launch_bounds__(256) void k_sum(const _Float16* __restrict__ A,
                                             const _Float16* __restrict__ B,
                                             _Float16* __restrict__ O) {
  const size_t i = ((size_t)blockIdx.x * 256 + threadIdx.x) * 8;
  const h8 a = *(const h8*)(A + i);
  const h8 b = *(const h8*)(B + i);
  *(h8*)(O + i) = a + b;
}

// ---- k_qf v5: grid 512 = 128 z-tiles x 4 i-chunks; block 256 = 4 waves (2zg x 2kg).
// Wave 64z x 64k. Phases = (i, j-half): [128k][64j] 16 KB; 4 buffers, stage 3
// ahead, vmcnt(8), ONE barrier per phase (stage issued after barrier).
__global__ __launch_bounds__(256, 2) void k_qf(const float* __restrict__ features,
                                               const _Float16* __restrict__ K3,
                                               float* __restrict__ out) {
  __shared__ __align__(16) _Float16 Bq[32768];  // 64 KB = 4 x 16 KB buffers
  __shared__ _Float16 fT[32 * 140];             // [i][z], stride 140
  const int t = threadIdx.x, lane = t & 63, w = t >> 6;
  const int zg = w >> 1, kg = w & 1, hg = lane >> 5, l31 = lane & 31;
  const int zb = (int)blockIdx.x >> 2, ic = (int)blockIdx.x & 3;
  const int z0 = zb * 128, i0 = ic * 32;

  // f-tile [z 0..127][j 0..127] f16, XOR-swizzled, into Bq[0..31KB] (transient)
  {
    const int row = t >> 1, hf = t & 1;
    const float* fr = features + (size_t)(z0 + row) * NIN;
    const int rs = (row & 7) << 4;
#pragma unroll
    for (int qb = 0; qb < 8; ++qb) {
      h8 v;
#pragma unroll
      for (int e = 0; e < 8; ++e) {
        const int j = hf * 64 + qb * 8 + e;
        v[e] = (j == 0) ? (_Float16)1.0f : (_Float16)fr[j - 1];
      }
      *(h8*)((char*)Bq + row * 256 + (((hf * 8 + qb) * 16) ^ rs)) = v;
    }
  }
  // fT fill: thread owns i = t&31, z-run (t>>5)*16..+15; packed b32 (z-pairs)
  {
    const int il = t & 31, zr0 = (t >> 5) * 16;
    const int gi = i0 + il;
#pragma unroll
    for (int zo = 0; zo < 8; ++zo) {
      const int z = zr0 + 2 * zo;
      const float v0 = (gi == 0) ? 1.0f : features[(size_t)(z0 + z) * NIN + gi - 1];
      const float v1 = (gi == 0) ? 1.0f : features[(size_t)(z0 + z + 1) * NIN + gi - 1];
      *(unsigned int*)((char*)fT + il * 280 + z * 2) = pk16(v0, v1);
    }
  }
  __syncthreads();

  // fj regs: rows (zg*64 + m*32 + l31), j = c*16 + hg*8 + e, c 0..7
  h8 fj8[2][8];
#pragma unroll
  for (int m = 0; m < 2; ++m) {
    const int rowm = zg * 64 + m * 32 + l31;
    const int rs = (rowm & 7) << 4;
#pragma unroll
    for (int c = 0; c < 8; ++c)
      fj8[m][c] = *(const h8*)((const char*)Bq + rowm * 256 + (((c * 2 + hg) * 16) ^ rs));
  }
  __syncthreads();  // fj reads done before staging overwrites Bq

  const int sl7 = l31 & 7;
  const int brow0 = (kg * 64 + l31) * 128;
  const int brow1 = (kg * 64 + 32 + l31) * 128;
  f32x16 acc[2][2] = {};

#define STAGEQ(BI, P)                                                            \
  {                                                                              \
    const _Float16* src = K3 + (size_t)(i0 + ((P) >> 1)) * 128 + ((P) & 1) * 64; \
    _Pragma("unroll") for (int r = 0; r < 4; ++r) {                              \
      const int rowb = w * 32 + r * 8 + (lane >> 3);                             \
      gl16(src + (size_t)rowb * PTOT + (((lane & 7) ^ (lane >> 3)) << 3),        \
           (char*)Bq + (BI) * 16384 + w * 4096 + r * 1024);                      \
    }                                                                            \
  }

#define PHASEQ(BI, CB, IPH, DOST, SP, VM)                                        \
  {                                                                              \
    const _Float16 f0s = fT[(IPH) * 140 + zg * 64 + l31];                        \
    const _Float16 f1s = fT[(IPH) * 140 + zg * 64 + 32 + l31];                   \
    const h2 fi0 = {f0s, f0s};                                                   \
    const h2 fi1 = {f1s, f1s};                                                   \
    h8 a0[4], a1[4];                                                             \
    _Pragma("unroll") for (int kl = 0; kl < 4; ++kl) {                           \
      const h8 fjA = fj8[0][(CB) + kl], fjB = fj8[1][(CB) + kl];                 \
      _Pragma("unroll") for (int r = 0; r < 4; ++r) {                            \
        const h2 j0 = {fjA[2 * r], fjA[2 * r + 1]};                              \
        const h2 j1 = {fjB[2 * r], fjB[2 * r + 1]};                              \
        const h2 q0 = fi0 * j0;                                                  \
        const h2 q1 = fi1 * j1;                                                  \
        a0[kl][2 * r] = q0[0]; a0[kl][2 * r + 1] = q0[1];                        \
        a1[kl][2 * r] = q1[0]; a1[kl][2 * r + 1] = q1[1];                        \
      }                                                                          \
    }                                                                            \
    asm volatile("s_waitcnt vmcnt(" #VM ")" ::: "memory");                       \
    __builtin_amdgcn_s_barrier();                                                \
    __builtin_amdgcn_sched_barrier(0);                                           \
    if (DOST) STAGEQ((SP) & 3, SP)                                               \
    __builtin_amdgcn_s_setprio(1);                                               \
    const char* bp = (const char*)Bq + (BI) * 16384;                             \
    _Pragma("unroll") for (int kl = 0; kl < 4; ++kl) {                           \
      const int ur = ((kl * 2 + hg) ^ sl7) << 4;                                 \
      const h8 b0 = *(const h8*)(bp + brow0 + ur);                               \
      const h8 b1 = *(const h8*)(bp + brow1 + ur);                               \
      acc[0][0] = __builtin_amdgcn_mfma_f32_32x32x16_f16(a0[kl], b0, acc[0][0], 0, 0, 0); \
      acc[0][1] = __builtin_amdgcn_mfma_f32_32x32x16_f16(a0[kl], b1, acc[0][1], 0, 0, 0); \
      acc[1][0] = __builtin_amdgcn_mfma_f32_32x32x16_f16(a1[kl], b0, acc[1][0], 0, 0, 0); \
      acc[1][1] = __builtin_amdgcn_mfma_f32_32x32x16_f16(a1[kl], b1, acc[1][1], 0, 0, 0); \
    }                                                                            \
    __builtin_amdgcn_s_setprio(0);                                               \
    __builtin_amdgcn_sched_barrier(0);                                           \
  }

  // prologue: 3 stages in flight (12 loads/wave)
  STAGEQ(0, 0)
  STAGEQ(1, 1)
  STAGEQ(2, 2)
  for (int pb = 0; pb < 30; ++pb) {
    PHASEQ((2 * pb) & 3, 0, pb, 1, 2 * pb + 3, 8)
    PHASEQ((2 * pb + 1) & 3, 4, pb, 1, 2 * pb + 4, 8)
  }
  PHASEQ(0, 0, 30, 1, 63, 8)  // phase 60, stages phase 63
  PHASEQ(1, 4, 30, 0, 0, 8)   // phase 61
  PHASEQ(2, 0, 31, 0, 0, 4)   // phase 62
  PHASEQ(3, 4, 31, 0, 0, 0)   // phase 63
#undef STAGEQ
#undef PHASEQ

  // C/D 32x32: col = l31 (k), row = (r&3) + 8*(r>>2) + 4*hg (z)
  const int kq = kg * 64 + l31;
#pragma unroll
  for (int m = 0; m < 2; ++m)
#pragma unroll
    for (int n = 0; n < 2; ++n)
#pragma unroll
      for (int r = 0; r < 16; ++r) {
        const int zr = (r & 3) + ((r >> 2) << 3) + (hg << 2);
        const int z = z0 + zg * 64 + m * 32 + zr;
        atomicAdd(out + (size_t)z * KOUT + kq + n * 32, acc[m][n][r]);
      }
}

extern "C" void kernel_launch(void* const* d_in, const int* in_sizes, int n_in,
                              void* d_out, int out_size, void* d_ws, size_t ws_size,
                              hipStream_t stream) {
  const float* features = (const float*)d_in[0];  // [16384, 127]
  const float* W        = (const float*)d_in[1];  // [128, 2080]
  const float* T        = (const float*)d_in[2];  // [2080, 16384]
  float* out = (float*)d_out;                     // [16384, 128] f32

  _Float16* K3h = (_Float16*)d_ws;                // [128, 16384] f16 (4 MB)
  _Float16* Wf  = K3h + (size_t)2 * 1024 * 1024;  // 532 KB, ws total ~4.6 MB
  _Float16* K3a = (_Float16*)d_out;               // partials in d_out scratch (8 MB)
  _Float16* K3b = K3a + (size_t)2 * 1024 * 1024;

  k_wf<<<dim3(130), dim3(256), 0, stream>>>(W, Wf);
  k_wt<<<dim3(256), dim3(256), 0, stream>>>(T, Wf, K3a, K3b);
  k_sum<<<dim3(1024), dim3(256), 0, stream>>>(K3a, K3b, K3h);
  (void)hipMemsetAsync(d_out, 0, (size_t)ZTOT * KOUT * sizeof(float), stream);
  k_qf<<<dim3(512), dim3(256), 0, stream>>>(features, K3h, out);
}